// Round 3
// baseline (1242.357 us; speedup 1.0000x reference)
//
#include <hip/hip_runtime.h>

#define NG 16
#define NC 4
#define BPB 8      // batch items per block
#define TSTEPS 8
#define NCHUNK 20  // (c,u) weight chunks per step

__device__ __forceinline__ void fma8(float w, const float4& s0, const float4& s1,
                                     float4& a0, float4& a1) {
    a0.x = fmaf(w, s0.x, a0.x);
    a0.y = fmaf(w, s0.y, a0.y);
    a0.z = fmaf(w, s0.z, a0.z);
    a0.w = fmaf(w, s0.w, a0.w);
    a1.x = fmaf(w, s1.x, a1.x);
    a1.y = fmaf(w, s1.y, a1.y);
    a1.z = fmaf(w, s1.z, a1.z);
    a1.w = fmaf(w, s1.w, a1.w);
}

__device__ __forceinline__ float4 lrelu4(float4 v) {
    float4 r;
    r.x = v.x > 0.f ? v.x : 0.1f * v.x;
    r.y = v.y > 0.f ? v.y : 0.1f * v.y;
    r.z = v.z > 0.f ? v.z : 0.1f * v.z;
    r.w = v.w > 0.f ? v.w : 0.1f * v.w;
    return r;
}

// Wt[(c*25+u*5+v)*256 + pix] : float4 over o, OOB (u,v) pre-zeroed.
// Per weight-load instruction: 64 consecutive lanes x 16B = fully coalesced.
// Original W: [y][x][o][c][u][v] (flat: pix*400 + o*100 + c*25 + u*5 + v)
__global__ void wt_transpose(const float* __restrict__ W, float4* __restrict__ Wt) {
    int t = blockIdx.x * 256 + threadIdx.x;   // 0..25599
    if (t >= 25600) return;
    int r = t >> 8;            // c*25 + u*5 + v
    int pix = t & 255;
    int c = r / 25, uv = r - c * 25, u = uv / 5, v = uv - u * 5;
    int y = pix >> 4, x = pix & 15;
    float4 w = make_float4(0.f, 0.f, 0.f, 0.f);
    if ((unsigned)(y + u - 2) < 16u && (unsigned)(x + v - 2) < 16u) {
        int base = pix * 400 + c * 25 + uv;
        w.x = W[base];
        w.y = W[base + 100];
        w.z = W[base + 200];
        w.w = W[base + 300];
    }
    Wt[r * 256 + pix] = w;
}

// Thread = pixel (owns all 4 output channels; 1 B LDS-delivery per FMA).
// LDS: float4 smv[buf][c][y][x][2 slots], phys slot = logical ^ ((x>>2)&1).
// Weights: distance-2 pipelined stream through 4 rotating 5xfloat4 buffers.
__global__ __launch_bounds__(256, 2)
void reservoir_kernel(const float* __restrict__ X, const float4* __restrict__ Wt,
                      float* __restrict__ out, int batch) {
    __shared__ float4 smv[2 * NC * NG * NG * 2];   // 65536 B
    float* smf = reinterpret_cast<float*>(smv);

    const int tid = threadIdx.x;        // pixel index
    const int y = tid >> 4;
    const int x = tid & 15;
    const long itemBase = (long)blockIdx.x * BPB;

    // ---- init: X (first 784 of 1024 slots) -> LDS buf 0 ----
    for (int b = 0; b < BPB; ++b) {
        long item = itemBase + b;
        const float* xr = X + item * 784;
        const int g = b >> 2, j = b & 3;
        #pragma unroll
        for (int kk = 0; kk < 4; ++kk) {
            int idx = tid + kk * 256;
            float v = 0.f;
            if (idx < 784 && item < batch) v = xr[idx];
            int c = idx >> 8, rem = idx & 255, yy = rem >> 4, xx = rem & 15;
            int phys = g ^ ((xx >> 2) & 1);
            smf[(((c * NG + yy) * NG + xx) << 3) + phys * 4 + j] = v;
        }
    }

    int ybf[5], xbf[5];
    #pragma unroll
    for (int u = 0; u < 5; ++u) {
        int yy = y + u - 2;
        yy = yy < 0 ? 0 : (yy > 15 ? 15 : yy);
        ybf[u] = yy * (NG * 2);
    }
    #pragma unroll
    for (int v = 0; v < 5; ++v) {
        int xv = x + v - 2;
        xv = xv < 0 ? 0 : (xv > 15 ? 15 : xv);
        xbf[v] = xv * 2 + ((xv >> 2) & 1);
    }
    const int swx = (x >> 2) & 1;

    // weight pipeline: 4 buffers x 5 float4 (80 VGPR), distance 2
    const float4* Wp = Wt + tid;
    float4 wb0[5], wb1[5], wb2[5], wb3[5];
    #pragma unroll
    for (int v = 0; v < 5; ++v) wb0[v] = Wp[v * 256];
    #pragma unroll
    for (int v = 0; v < 5; ++v) wb1[v] = Wp[(5 + v) * 256];

    __syncthreads();

    #pragma unroll 1
    for (int t = 0; t < TSTEPS; ++t) {
        const int rbase = (t & 1) << 11;   // 2048 float4 per buffer
        float4 a00 = {0,0,0,0}, a01 = {0,0,0,0};
        float4 a10 = {0,0,0,0}, a11 = {0,0,0,0};
        float4 a20 = {0,0,0,0}, a21 = {0,0,0,0};
        float4 a30 = {0,0,0,0}, a31 = {0,0,0,0};

        #pragma unroll
        for (int k = 0; k < NCHUNK; ++k) {
            const int c = k / 5, u = k - c * 5;
            // prefetch chunk (k+2)%20 into buffer (k+2)%4  (20%4==0 -> t-invariant)
            {
                const int kp = (k + 2) % NCHUNK;
                float4* dst = ((k + 2) % 4 == 0) ? wb0 : ((k + 2) % 4 == 1) ? wb1
                            : ((k + 2) % 4 == 2) ? wb2 : wb3;
                #pragma unroll
                for (int v = 0; v < 5; ++v) dst[v] = Wp[(kp * 5 + v) * 256];
            }
            const float4* wc = (k % 4 == 0) ? wb0 : (k % 4 == 1) ? wb1
                             : (k % 4 == 2) ? wb2 : wb3;
            const int sbase = rbase + c * 512 + ybf[u];
            #pragma unroll
            for (int v = 0; v < 5; ++v) {
                const int i0 = sbase + xbf[v];
                const float4 s0 = smv[i0];        // batches 0-3
                const float4 s1 = smv[i0 ^ 1];    // batches 4-7
                const float4 w4 = wc[v];
                fma8(w4.x, s0, s1, a00, a01);
                fma8(w4.y, s0, s1, a10, a11);
                fma8(w4.z, s0, s1, a20, a21);
                fma8(w4.w, s0, s1, a30, a31);
            }
        }

        a00 = lrelu4(a00); a01 = lrelu4(a01);
        a10 = lrelu4(a10); a11 = lrelu4(a11);
        a20 = lrelu4(a20); a21 = lrelu4(a21);
        a30 = lrelu4(a30); a31 = lrelu4(a31);

        if (t < TSTEPS - 1) {
            const int wbase = rbase ^ 2048;
            const int pa = (y * NG + x) * 2;
            int b0 = wbase + 0 * 512 + pa;
            smv[b0 + swx] = a00; smv[b0 + (swx ^ 1)] = a01;
            int b1 = wbase + 1 * 512 + pa;
            smv[b1 + swx] = a10; smv[b1 + (swx ^ 1)] = a11;
            int b2 = wbase + 2 * 512 + pa;
            smv[b2 + swx] = a20; smv[b2 + (swx ^ 1)] = a21;
            int b3 = wbase + 3 * 512 + pa;
            smv[b3 + swx] = a30; smv[b3 + (swx ^ 1)] = a31;
            __syncthreads();
        } else {
            float4 p0, p1;
            p0.x = (a00.x + a10.x + a20.x + a30.x) * 0.25f;
            p0.y = (a00.y + a10.y + a20.y + a30.y) * 0.25f;
            p0.z = (a00.z + a10.z + a20.z + a30.z) * 0.25f;
            p0.w = (a00.w + a10.w + a20.w + a30.w) * 0.25f;
            p1.x = (a01.x + a11.x + a21.x + a31.x) * 0.25f;
            p1.y = (a01.y + a11.y + a21.y + a31.y) * 0.25f;
            p1.z = (a01.z + a11.z + a21.z + a31.z) * 0.25f;
            p1.w = (a01.w + a11.w + a21.w + a31.w) * 0.25f;
            long ob = itemBase * 256 + tid;
            if (itemBase + 0 < batch) out[ob + 0 * 256] = p0.x;
            if (itemBase + 1 < batch) out[ob + 1 * 256] = p0.y;
            if (itemBase + 2 < batch) out[ob + 2 * 256] = p0.z;
            if (itemBase + 3 < batch) out[ob + 3 * 256] = p0.w;
            if (itemBase + 4 < batch) out[ob + 4 * 256] = p1.x;
            if (itemBase + 5 < batch) out[ob + 5 * 256] = p1.y;
            if (itemBase + 6 < batch) out[ob + 6 * 256] = p1.z;
            if (itemBase + 7 < batch) out[ob + 7 * 256] = p1.w;
        }
    }
}

extern "C" void kernel_launch(void* const* d_in, const int* in_sizes, int n_in,
                              void* d_out, int out_size, void* d_ws, size_t ws_size,
                              hipStream_t stream) {
    const float* X = (const float*)d_in[0];
    const float* W = (const float*)d_in[1];
    float* out = (float*)d_out;
    const int batch = in_sizes[0] / 784;            // 8192
    const int blocks = (batch + BPB - 1) / BPB;     // 1024

    wt_transpose<<<100, 256, 0, stream>>>(W, (float4*)d_ws);
    reservoir_kernel<<<blocks, 256, 0, stream>>>(
        X, (const float4*)d_ws, out, batch);
}

// Round 4
// 517.588 us; speedup vs baseline: 2.4003x; 2.4003x over previous
//
#include <hip/hip_runtime.h>

#define NG 16
#define NC 4
#define BPB 8      // batch items per block
#define TSTEPS 8

__device__ __forceinline__ void fma8(float w, const float4& s0, const float4& s1,
                                     float4& a0, float4& a1) {
    a0.x = fmaf(w, s0.x, a0.x);
    a0.y = fmaf(w, s0.y, a0.y);
    a0.z = fmaf(w, s0.z, a0.z);
    a0.w = fmaf(w, s0.w, a0.w);
    a1.x = fmaf(w, s1.x, a1.x);
    a1.y = fmaf(w, s1.y, a1.y);
    a1.z = fmaf(w, s1.z, a1.z);
    a1.w = fmaf(w, s1.w, a1.w);
}

__device__ __forceinline__ float4 lrelu4(float4 v) {
    float4 r;
    r.x = v.x > 0.f ? v.x : 0.1f * v.x;
    r.y = v.y > 0.f ? v.y : 0.1f * v.y;
    r.z = v.z > 0.f ? v.z : 0.1f * v.z;
    r.w = v.w > 0.f ? v.w : 0.1f * v.w;
    return r;
}

// Wt[(c*25+u*5+v)*256 + pix] : float4 over o, OOB (u,v) pre-zeroed.
// Original W: [y][x][o][c][u][v] (flat: pix*400 + o*100 + c*25 + u*5 + v)
__global__ void wt_transpose(const float* __restrict__ W, float4* __restrict__ Wt) {
    int t = blockIdx.x * 256 + threadIdx.x;   // 0..25599
    if (t >= 25600) return;
    int r = t >> 8;            // c*25 + u*5 + v
    int pix = t & 255;
    int c = r / 25, uv = r - c * 25, u = uv / 5, v = uv - u * 5;
    int y = pix >> 4, x = pix & 15;
    float4 w = make_float4(0.f, 0.f, 0.f, 0.f);
    if ((unsigned)(y + u - 2) < 16u && (unsigned)(x + v - 2) < 16u) {
        int base = pix * 400 + c * 25 + uv;
        w.x = W[base];
        w.y = W[base + 100];
        w.z = W[base + 200];
        w.w = W[base + 300];
    }
    Wt[r * 256 + pix] = w;
}

// Thread = pixel; owns all 4 output channels for 8 batch items.
// LDS: float4 smv[buf][c][y][x][2 slots], phys slot = logical ^ ((x>>2)&1).
// Weights: distance-3 pipelined stream through 5 register buffers of 5 float4,
// ALL named scalars (no arrays, no pointer selection -> guaranteed SROA).
__global__ __launch_bounds__(256, 2)
void reservoir_kernel(const float* __restrict__ X, const float4* __restrict__ Wt,
                      float* __restrict__ out, int batch) {
    __shared__ float4 smv[2 * NC * NG * NG * 2];   // 65536 B
    float* smf = reinterpret_cast<float*>(smv);

    const int tid = threadIdx.x;        // pixel index
    const int y = tid >> 4;
    const int x = tid & 15;
    const long itemBase = (long)blockIdx.x * BPB;

    const float4* Wp = Wt + tid;

    // ---- weight pipeline registers: 5 buffers x 5 float4, named ----
    float4 b0_0, b0_1, b0_2, b0_3, b0_4;
    float4 b1_0, b1_1, b1_2, b1_3, b1_4;
    float4 b2_0, b2_1, b2_2, b2_3, b2_4;
    float4 b3_0, b3_1, b3_2, b3_3, b3_4;
    float4 b4_0, b4_1, b4_2, b4_3, b4_4;

    // chunk k (= c*5+u) occupies Wp offsets k*1280 + v*256, v=0..4
#define LOADBUF(B, OFF) \
    B##_0 = Wp[(OFF)]; \
    B##_1 = Wp[(OFF) + 256]; \
    B##_2 = Wp[(OFF) + 512]; \
    B##_3 = Wp[(OFF) + 768]; \
    B##_4 = Wp[(OFF) + 1024];

    // prologue: chunks 0,1,2 -> buffers 0,1,2
    LOADBUF(b0, 0)
    LOADBUF(b1, 1280)
    LOADBUF(b2, 2560)

    // ---- init: X (first 784 of 1024 slots) -> LDS buf 0 (nontemporal) ----
    for (int b = 0; b < BPB; ++b) {
        long item = itemBase + b;
        const float* xr = X + item * 784;
        const int g = b >> 2, j = b & 3;
        #pragma unroll
        for (int kk = 0; kk < 4; ++kk) {
            int idx = tid + kk * 256;
            float v = 0.f;
            if (idx < 784 && item < batch) v = __builtin_nontemporal_load(&xr[idx]);
            int c = idx >> 8, rem = idx & 255, yy = rem >> 4, xx = rem & 15;
            int phys = g ^ ((xx >> 2) & 1);
            smf[(((c * NG + yy) * NG + xx) << 3) + phys * 4 + j] = v;
        }
    }

    int ybf[5], xbf[5];
    #pragma unroll
    for (int u = 0; u < 5; ++u) {
        int yy = y + u - 2;
        yy = yy < 0 ? 0 : (yy > 15 ? 15 : yy);
        ybf[u] = yy * (NG * 2);
    }
    #pragma unroll
    for (int v = 0; v < 5; ++v) {
        int xv = x + v - 2;
        xv = xv < 0 ? 0 : (xv > 15 ? 15 : xv);
        xbf[v] = xv * 2 + ((xv >> 2) & 1);
    }
    const int swx = (x >> 2) & 1;

    __syncthreads();

#define FMA_V(WV, V) { \
    const int i0 = sbase + xbf[V]; \
    const float4 s0 = smv[i0]; \
    const float4 s1 = smv[i0 ^ 1]; \
    fma8(WV.x, s0, s1, a00, a01); \
    fma8(WV.y, s0, s1, a10, a11); \
    fma8(WV.z, s0, s1, a20, a21); \
    fma8(WV.w, s0, s1, a30, a31); }

    // consume buffer B (chunk (c=g, u=U)); prefetch chunk at POFF into PB
#define CHUNK(B, U, PB, POFF) \
    LOADBUF(PB, POFF) \
    { const int sbase = sb + ybf[U]; \
      FMA_V(B##_0, 0) FMA_V(B##_1, 1) FMA_V(B##_2, 2) FMA_V(B##_3, 3) FMA_V(B##_4, 4) }

    #pragma unroll 1
    for (int t = 0; t < TSTEPS; ++t) {
        const int rbase = (t & 1) << 11;   // 2048 float4 per state buffer
        float4 a00 = {0,0,0,0}, a01 = {0,0,0,0};
        float4 a10 = {0,0,0,0}, a11 = {0,0,0,0};
        float4 a20 = {0,0,0,0}, a21 = {0,0,0,0};
        float4 a30 = {0,0,0,0}, a31 = {0,0,0,0};

        #pragma unroll 1
        for (int g = 0; g < 4; ++g) {       // chunk k = g*5 + j ; c = g, u = j
            const int g1 = (g == 3) ? 0 : g + 1;
            const int wg  = g  * 6400;      // = (g*5)*1280
            const int wg1 = g1 * 6400;
            const int sb = rbase + g * 512; // c = g

            CHUNK(b0, 0, b3, wg + 3840)     // prefetch chunk 5g+3
            CHUNK(b1, 1, b4, wg + 5120)     // prefetch chunk 5g+4
            CHUNK(b2, 2, b0, wg1)           // prefetch chunk 5(g+1)+0 (mod 20)
            CHUNK(b3, 3, b1, wg1 + 1280)    // prefetch chunk 5(g+1)+1
            CHUNK(b4, 4, b2, wg1 + 2560)    // prefetch chunk 5(g+1)+2
        }

        a00 = lrelu4(a00); a01 = lrelu4(a01);
        a10 = lrelu4(a10); a11 = lrelu4(a11);
        a20 = lrelu4(a20); a21 = lrelu4(a21);
        a30 = lrelu4(a30); a31 = lrelu4(a31);

        if (t < TSTEPS - 1) {
            const int wbase = rbase ^ 2048;
            const int pa = (y * NG + x) * 2;
            int c0 = wbase + 0 * 512 + pa;
            smv[c0 + swx] = a00; smv[c0 + (swx ^ 1)] = a01;
            int c1 = wbase + 1 * 512 + pa;
            smv[c1 + swx] = a10; smv[c1 + (swx ^ 1)] = a11;
            int c2 = wbase + 2 * 512 + pa;
            smv[c2 + swx] = a20; smv[c2 + (swx ^ 1)] = a21;
            int c3 = wbase + 3 * 512 + pa;
            smv[c3 + swx] = a30; smv[c3 + (swx ^ 1)] = a31;
            __syncthreads();
        } else {
            float4 p0, p1;
            p0.x = (a00.x + a10.x + a20.x + a30.x) * 0.25f;
            p0.y = (a00.y + a10.y + a20.y + a30.y) * 0.25f;
            p0.z = (a00.z + a10.z + a20.z + a30.z) * 0.25f;
            p0.w = (a00.w + a10.w + a20.w + a30.w) * 0.25f;
            p1.x = (a01.x + a11.x + a21.x + a31.x) * 0.25f;
            p1.y = (a01.y + a11.y + a21.y + a31.y) * 0.25f;
            p1.z = (a01.z + a11.z + a21.z + a31.z) * 0.25f;
            p1.w = (a01.w + a11.w + a21.w + a31.w) * 0.25f;
            long ob = itemBase * 256 + tid;
            if (itemBase + 0 < batch) __builtin_nontemporal_store(p0.x, &out[ob + 0 * 256]);
            if (itemBase + 1 < batch) __builtin_nontemporal_store(p0.y, &out[ob + 1 * 256]);
            if (itemBase + 2 < batch) __builtin_nontemporal_store(p0.z, &out[ob + 2 * 256]);
            if (itemBase + 3 < batch) __builtin_nontemporal_store(p0.w, &out[ob + 3 * 256]);
            if (itemBase + 4 < batch) __builtin_nontemporal_store(p1.x, &out[ob + 4 * 256]);
            if (itemBase + 5 < batch) __builtin_nontemporal_store(p1.y, &out[ob + 5 * 256]);
            if (itemBase + 6 < batch) __builtin_nontemporal_store(p1.z, &out[ob + 6 * 256]);
            if (itemBase + 7 < batch) __builtin_nontemporal_store(p1.w, &out[ob + 7 * 256]);
        }
    }
}

extern "C" void kernel_launch(void* const* d_in, const int* in_sizes, int n_in,
                              void* d_out, int out_size, void* d_ws, size_t ws_size,
                              hipStream_t stream) {
    const float* X = (const float*)d_in[0];
    const float* W = (const float*)d_in[1];
    float* out = (float*)d_out;
    const int batch = in_sizes[0] / 784;            // 8192
    const int blocks = (batch + BPB - 1) / BPB;     // 1024

    wt_transpose<<<100, 256, 0, stream>>>(W, (float4*)d_ws);
    reservoir_kernel<<<blocks, 256, 0, stream>>>(
        X, (const float4*)d_ws, out, batch);
}